// Round 12
// baseline (107.250 us; speedup 1.0000x reference)
//
#include <hip/hip_runtime.h>

// Problem constants (fixed by setup_inputs: N=8192, D=8, fp32).
constexpr int N = 8192;
constexpr int BLK = 256;           // threads per block (4 waves)
constexpr int JSPLIT = 32;         // j-range splits -> grid 32*32*2 = 2048 = 8 blk/CU
constexpr int JSEG = N / JSPLIT;   // 256 j-rows per block

typedef float f32x4 __attribute__((ext_vector_type(4)));
typedef uint32_t u32x16 __attribute__((ext_vector_type(16)));

// j-rows through the SCALAR path: one s_load_dwordx16 = 2 rows.
#define SLOAD16(dst, base, immstr) \
  asm volatile("s_load_dwordx16 %0, %1, " immstr : "=s"(dst) : "s"(base))

__device__ __forceinline__ float max3f(float a, float b, float c) {
  float r;
  asm("v_max3_f32 %0, %1, %2, %3" : "=v"(r) : "v"(a), "v"(b), "v"(c));
  return r;
}
__device__ __forceinline__ float max2f(float a, float b) {
  float r;
  asm("v_max_f32 %0, %1, %2" : "=v"(r) : "v"(a), "v"(b));
  return r;
}

// counts[m*N + i] = #{ j : M[i,d] > M[j,d] for all d }
// One j-row (SGPR broadcast) vs 64 i-rows (lanes). Strict dominance:
// max_d(M[j,d] - M[i,d]) < 0. Ties/self give max >= -0.0 -> rejected
// (same exact semantics validated absmax 0.0 in R1-R9, R11).
// R12: INDEPENDENT 8x v_sub (1 SGPR src each) + v_max3 tree + cmp/addc —
// 14 hazard-free VALU per 64 pairs. Replaces R11's 8 chained v_cmpx whose
// EXEC-write dependency made each cost ~4cyc (26us busy, 43% stall).
#define JROW(q, e)                                                       \
  {                                                                      \
    const float d0 = __uint_as_float(q[e + 0]) - xi0;                    \
    const float d1 = __uint_as_float(q[e + 1]) - xi1;                    \
    const float d2 = __uint_as_float(q[e + 2]) - xi2;                    \
    const float d3 = __uint_as_float(q[e + 3]) - xi3;                    \
    const float d4 = __uint_as_float(q[e + 4]) - xi4;                    \
    const float d5 = __uint_as_float(q[e + 5]) - xi5;                    \
    const float d6 = __uint_as_float(q[e + 6]) - xi6;                    \
    const float d7 = __uint_as_float(q[e + 7]) - xi7;                    \
    const float t0 = max3f(d0, d1, d2);                                  \
    const float t1 = max3f(d3, d4, d5);                                  \
    const float t2 = max3f(d6, d7, t0);                                  \
    cnt += (max2f(t1, t2) < 0.0f) ? 1 : 0;                               \
  }

__global__ __launch_bounds__(BLK, 4) void dom_count_kernel(
    const float* __restrict__ X, const float* __restrict__ Xh,
    int* __restrict__ counts) {
  const float* __restrict__ M = (blockIdx.z == 0) ? X : Xh;
  int* cnt_out = counts + blockIdx.z * N;

  const int i = blockIdx.x * BLK + threadIdx.x;

  // my i-row in 8 lane registers
  const f32x4* Mi = reinterpret_cast<const f32x4*>(M + (size_t)i * 8);
  const f32x4 ra = Mi[0];
  const f32x4 rb = Mi[1];
  const float xi0 = ra.x, xi1 = ra.y, xi2 = ra.z, xi3 = ra.w;
  const float xi4 = rb.x, xi5 = rb.y, xi6 = rb.z, xi7 = rb.w;

  int cnt = 0;
  const float* jb = M + (size_t)(blockIdx.y * JSEG) * 8;
  for (int jj = 0; jj < JSEG; jj += 8) {
    u32x16 q0, q1, q2, q3;
    const float* gb = jb + (size_t)jj * 8;
    SLOAD16(q0, gb, "0x0");
    SLOAD16(q1, gb, "0x40");
    SLOAD16(q2, gb, "0x80");
    SLOAD16(q3, gb, "0xC0");
    // R11-proven fix: thread the tuples THROUGH the waitcnt as "+s" in/outs
    // so element extraction cannot be hoisted above the wait (s_load is
    // async; SMEM completes out of order -> only lgkmcnt(0) is safe).
    asm volatile("s_waitcnt lgkmcnt(0)"
                 : "+s"(q0), "+s"(q1), "+s"(q2), "+s"(q3));
    JROW(q0, 0)
    JROW(q0, 8)
    JROW(q1, 0)
    JROW(q1, 8)
    JROW(q2, 0)
    JROW(q2, 8)
    JROW(q3, 0)
    JROW(q3, 8)
  }

  atomicAdd(&cnt_out[i], cnt);
}

// --- Finalize, stage 1: privatized histograms (R3-proven) -------------------
// sum_k |sort(a)_k - sort(b)_k| == sum_t |#{a<=t} - #{b<=t}|; histogram +1 for
// X counts, -1 for Xh counts. 16 blocks privatize hot-bin contention.
constexpr int HB = 16;
__global__ __launch_bounds__(1024) void hist_partial_kernel(
    const int* __restrict__ counts, int* __restrict__ ghist) {
  __shared__ int lhist[N];  // 32 KB
  const int tid = threadIdx.x;
  for (int q = tid; q < N; q += 1024) lhist[q] = 0;
  __syncthreads();

  const int k = blockIdx.x * (2 * N / HB) + tid;  // 1024 values per block
  const int v = counts[k];
  atomicAdd(&lhist[v], (k < N) ? 1 : -1);
  __syncthreads();

#pragma unroll
  for (int q = 0; q < N / 1024; ++q) {
    const int bin = tid * (N / 1024) + q;
    const int h = lhist[bin];
    if (h != 0) atomicAdd(&ghist[bin], h);
  }
}

// --- Finalize, stage 2: scan + abs-sum (one small block, R3-proven) ---------
__global__ __launch_bounds__(1024) void finalize_kernel(
    const int* __restrict__ ghist, float* __restrict__ out) {
  __shared__ int wsum[16];
  __shared__ int wexc[16];
  __shared__ int wabs[16];

  const int tid = threadIdx.x;
  const int lane = tid & 63;
  const int wid = tid >> 6;

  int local[8];
  int s = 0;
#pragma unroll
  for (int q = 0; q < 8; ++q) {
    local[q] = ghist[tid * 8 + q];
    s += local[q];
  }

  int incl = s;  // wave-inclusive scan of per-thread sums
#pragma unroll
  for (int off = 1; off < 64; off <<= 1) {
    const int v = __shfl_up(incl, off);
    if (lane >= off) incl += v;
  }
  if (lane == 63) wsum[wid] = incl;
  __syncthreads();

  if (tid == 0) {
    int acc = 0;
#pragma unroll
    for (int w = 0; w < 16; ++w) { wexc[w] = acc; acc += wsum[w]; }
  }
  __syncthreads();

  int run = wexc[wid] + (incl - s);  // exclusive prefix of my 8-bin chunk
  int acc = 0;
#pragma unroll
  for (int q = 0; q < 8; ++q) {
    run += local[q];
    acc += (run < 0) ? -run : run;
  }

#pragma unroll
  for (int off = 32; off > 0; off >>= 1) acc += __shfl_down(acc, off);
  if (lane == 0) wabs[wid] = acc;
  __syncthreads();

  if (tid == 0) {
    int total = 0;
#pragma unroll
    for (int w = 0; w < 16; ++w) total += wabs[w];
    // result = total / (N-1) / N
    out[0] = (float)((double)total / ((double)(N - 1) * (double)N));
  }
}

extern "C" void kernel_launch(void* const* d_in, const int* in_sizes, int n_in,
                              void* d_out, int out_size, void* d_ws, size_t ws_size,
                              hipStream_t stream) {
  const float* X = (const float*)d_in[0];
  const float* Xh = (const float*)d_in[1];
  float* out = (float*)d_out;
  int* counts = (int*)d_ws;        // 2N ints
  int* ghist = counts + 2 * N;     // N ints, contiguous

  hipMemsetAsync(counts, 0, 3 * N * sizeof(int), stream);

  dim3 grid(N / BLK, JSPLIT, 2);
  dom_count_kernel<<<grid, BLK, 0, stream>>>(X, Xh, counts);
  hist_partial_kernel<<<HB, 1024, 0, stream>>>(counts, ghist);
  finalize_kernel<<<1, 1024, 0, stream>>>(ghist, out);
}